// Round 6
// baseline (473.630 us; speedup 1.0000x reference)
//
#include <hip/hip_runtime.h>
#include <math.h>

#define N_EMBD 768
#define T_SEQ  1024
#define BATCH  8
#define NHEAD  12
#define HD     64
#define EPS    1e-5f
#define M_TOK  (BATCH * T_SEQ)   // 8192

typedef unsigned short u16;
typedef __attribute__((ext_vector_type(8))) short          s16x8;
typedef __attribute__((ext_vector_type(8))) unsigned short u16x8;
typedef __attribute__((ext_vector_type(4))) float          f32x4;

#define GLDS(gp, lp) \
    __builtin_amdgcn_global_load_lds( \
        (const __attribute__((address_space(1))) void*)(gp), \
        (__attribute__((address_space(3))) void*)(lp), 16, 0, 0)

__device__ __forceinline__ u16 f2bf(float f) {
    unsigned int u = __float_as_uint(f);
    u += 0x7fffu + ((u >> 16) & 1u);
    return (u16)(u >> 16);
}

// ---------------- weight convert + transpose: fp32 [R][C] -> bf16 [C][R] ----------------
__global__ __launch_bounds__(256) void wconv(const float* __restrict__ in,
                                             u16* __restrict__ out, int R, int C) {
    __shared__ float tile[64][65];
    int t = threadIdx.x;
    int r0 = blockIdx.y * 64, c0 = blockIdx.x * 64;
    int rl = t >> 4, c4 = (t & 15) * 4;
#pragma unroll
    for (int i = 0; i < 4; i++) {
        float4 v = *(const float4*)(in + (size_t)(r0 + rl + i * 16) * C + c0 + c4);
        tile[rl + i * 16][c4 + 0] = v.x;
        tile[rl + i * 16][c4 + 1] = v.y;
        tile[rl + i * 16][c4 + 2] = v.z;
        tile[rl + i * 16][c4 + 3] = v.w;
    }
    __syncthreads();
#pragma unroll
    for (int i = 0; i < 4; i++) {
        int crow = rl + i * 16;
        ushort4 s4;
        s4.x = f2bf(tile[c4 + 0][crow]);
        s4.y = f2bf(tile[c4 + 1][crow]);
        s4.z = f2bf(tile[c4 + 2][crow]);
        s4.w = f2bf(tile[c4 + 3][crow]);
        *(ushort4*)(out + (size_t)(c0 + crow) * R + r0 + c4) = s4;
    }
}

// ---------------- LayerNorm fp32 in -> bf16 out ----------------
__global__ __launch_bounds__(256) void ln_bf16(const float* __restrict__ x,
                                               const float* __restrict__ g,
                                               const float* __restrict__ b,
                                               u16* __restrict__ out) {
    int row = blockIdx.x;
    int tid = threadIdx.x;
    const float* xr = x + (size_t)row * N_EMBD;
    float v0 = xr[tid], v1 = xr[tid + 256], v2 = xr[tid + 512];
    float s1 = v0 + v1 + v2;
    float s2 = v0 * v0 + v1 * v1 + v2 * v2;
    __shared__ float red1[4], red2[4];
#pragma unroll
    for (int o = 32; o > 0; o >>= 1) {
        s1 += __shfl_down(s1, o);
        s2 += __shfl_down(s2, o);
    }
    if ((tid & 63) == 0) { red1[tid >> 6] = s1; red2[tid >> 6] = s2; }
    __syncthreads();
    float mean = (red1[0] + red1[1] + red1[2] + red1[3]) * (1.0f / N_EMBD);
    float ms   = (red2[0] + red2[1] + red2[2] + red2[3]) * (1.0f / N_EMBD);
    float rs = rsqrtf(ms - mean * mean + EPS);
    u16* orow = out + (size_t)row * N_EMBD;
    orow[tid]       = f2bf((v0 - mean) * rs * g[tid]       + b[tid]);
    orow[tid + 256] = f2bf((v1 - mean) * rs * g[tid + 256] + b[tid + 256]);
    orow[tid + 512] = f2bf((v2 - mean) * rs * g[tid + 512] + b[tid + 512]);
}

// ---------------- bf16 MFMA GEMM (round-4 structure: single 32KB LDS, 5 blocks/CU) ----
// C[M,N] = A[M,K] @ Bt[N,K]^T + bias; MODE 0: bf16 out; 1: bf16 gelu; 2: fp32 +res
template <int MODE>
__global__ __launch_bounds__(256) void gemm_bf16(const u16* __restrict__ A,
                                                 const u16* __restrict__ Bt,
                                                 const float* __restrict__ bias,
                                                 const float* __restrict__ res,
                                                 void* __restrict__ outp,
                                                 int M, int N, int K) {
    __shared__ u16 As[128][64];  // linear: glds dest
    __shared__ u16 Bs[128][64];
    int tid = threadIdx.x;
    int l = tid & 63, w = tid >> 6;
    int lr = l & 15, lg = l >> 4;
    int bm = blockIdx.y * 128, bn = blockIdx.x * 128;
    int wr = (w >> 1) * 64, wc = (w & 1) * 64;
    int srow = l >> 3, scol = (l & 7) * 8;
    f32x4 acc[4][4] = {};
    for (int k0 = 0; k0 < K; k0 += 64) {
        __syncthreads();
#pragma unroll
        for (int i = 0; i < 4; i++) {
            int c = i * 4 + w;
            int row = c * 8 + srow;
            GLDS(A  + (size_t)(bm + row) * K + k0 + scol, &As[c * 8][0]);
            GLDS(Bt + (size_t)(bn + row) * K + k0 + scol, &Bs[c * 8][0]);
        }
        __syncthreads();
#pragma unroll
        for (int kk = 0; kk < 2; kk++) {
            s16x8 af[4], bf[4];
#pragma unroll
            for (int i = 0; i < 4; i++) {
                af[i] = *(const s16x8*)&As[wr + i * 16 + lr][kk * 32 + lg * 8];
                bf[i] = *(const s16x8*)&Bs[wc + i * 16 + lr][kk * 32 + lg * 8];
            }
#pragma unroll
            for (int mi = 0; mi < 4; mi++)
#pragma unroll
                for (int nj = 0; nj < 4; nj++)
                    acc[mi][nj] = __builtin_amdgcn_mfma_f32_16x16x32_bf16(
                        af[mi], bf[nj], acc[mi][nj], 0, 0, 0);
        }
    }
#pragma unroll
    for (int mi = 0; mi < 4; mi++)
#pragma unroll
        for (int nj = 0; nj < 4; nj++)
#pragma unroll
            for (int r = 0; r < 4; r++) {
                int row = bm + wr + mi * 16 + lg * 4 + r;
                int col = bn + wc + nj * 16 + lr;
                float v = acc[mi][nj][r] + bias[col];
                if (MODE == 1) {
                    // gelu-tanh via exp (saturation-safe): v - v/(1+e^{2u})
                    float u = 1.5957691216057308f * (v + 0.044715f * v * v * v);
                    v = v - v / (1.0f + __expf(u));
                }
                if (MODE == 2) {
                    v += res[(size_t)row * N + col];
                    ((float*)outp)[(size_t)row * N + col] = v;
                } else {
                    ((u16*)outp)[(size_t)row * N + col] = f2bf(v);
                }
            }
}

// ---------------- flash attention, bf16 MFMA, causal, UNSCALED ----------------
// 768 uniform-start blocks (3/CU resident); dynamic dispatch absorbs qt imbalance
#define QBLK 128
#define SBLK 64
__global__ __launch_bounds__(256) void attn_mfma(const u16* __restrict__ qkv,
                                                 u16* __restrict__ outp) {
    __shared__ u16 Kl[SBLK][64];
    __shared__ u16 Vt[HD][72];
    __shared__ u16 Pl[4][32][72];
    int tid = threadIdx.x;
    int w = tid >> 6, l = tid & 63;
    int lr = l & 15, lg = l >> 4;
    int qt = blockIdx.x, h = blockIdx.y, b = blockIdx.z;
    int q0 = qt * QBLK;
    size_t bbase = (size_t)b * T_SEQ * (3 * N_EMBD);

    s16x8 qf[2][2];
#pragma unroll
    for (int rg = 0; rg < 2; rg++)
#pragma unroll
        for (int kk = 0; kk < 2; kk++) {
            int row = q0 + w * 32 + rg * 16 + lr;
            qf[rg][kk] = *(const s16x8*)(qkv + bbase + (size_t)row * (3 * N_EMBD) +
                                         h * HD + kk * 32 + lg * 8);
        }
    f32x4 oacc[2][4] = {};
    float mrun[2][4], lrun[2][4];
#pragma unroll
    for (int rg = 0; rg < 2; rg++)
#pragma unroll
        for (int r = 0; r < 4; r++) { mrun[rg][r] = -1e30f; lrun[rg][r] = 0.f; }

    int nt = 2 * qt + 2;
    for (int st = 0; st < nt; st++) {
        int s0 = st * SBLK;
#pragma unroll
        for (int i = 0; i < 2; i++) {
            int c = i * 4 + w;
            int row = c * 8 + (l >> 3);
            GLDS(qkv + bbase + (size_t)(s0 + row) * (3 * N_EMBD) + N_EMBD + h * HD + (l & 7) * 8,
                 &Kl[c * 8][0]);
        }
#pragma unroll
        for (int i = 0; i < 2; i++) {
            int c = i * 256 + tid;
            int sr = c >> 3, d0 = (c & 7) * 8;
            u16x8 vv = *(const u16x8*)(qkv + bbase + (size_t)(s0 + sr) * (3 * N_EMBD) +
                                       2 * N_EMBD + h * HD + d0);
            int sz = ((sr >> 3) ^ (d0 >> 3)) * 8 + (sr & 7);
#pragma unroll
            for (int j = 0; j < 8; j++) Vt[d0 + j][sz] = vv[j];
        }
        __syncthreads();
        f32x4 sacc[2][4] = {};
#pragma unroll
        for (int kk = 0; kk < 2; kk++) {
            s16x8 kf[4];
#pragma unroll
            for (int nj = 0; nj < 4; nj++)
                kf[nj] = *(const s16x8*)&Kl[nj * 16 + lr][kk * 32 + lg * 8];
#pragma unroll
            for (int rg = 0; rg < 2; rg++)
#pragma unroll
                for (int nj = 0; nj < 4; nj++)
                    sacc[rg][nj] = __builtin_amdgcn_mfma_f32_16x16x32_bf16(
                        qf[rg][kk], kf[nj], sacc[rg][nj], 0, 0, 0);
        }
#pragma unroll
        for (int rg = 0; rg < 2; rg++) {
            int qrow0 = q0 + w * 32 + rg * 16 + lg * 4;
            float mx[4];
#pragma unroll
            for (int r = 0; r < 4; r++) {
                int qi = qrow0 + r;
                float mv = -1e30f;
#pragma unroll
                for (int nj = 0; nj < 4; nj++) {
                    int si = s0 + nj * 16 + lr;
                    float v = sacc[rg][nj][r];
                    v = (si <= qi) ? v : -1e30f;
                    sacc[rg][nj][r] = v;
                    mv = fmaxf(mv, v);
                }
                mx[r] = mv;
            }
#pragma unroll
            for (int d = 1; d < 16; d <<= 1)
#pragma unroll
                for (int r = 0; r < 4; r++) mx[r] = fmaxf(mx[r], __shfl_xor(mx[r], d, 64));
            float rs[4];
#pragma unroll
            for (int r = 0; r < 4; r++) {
                float mnew = fmaxf(mrun[rg][r], mx[r]);
                float sc = __expf(mrun[rg][r] - mnew);
                mrun[rg][r] = mnew;
                float sum = 0.f;
#pragma unroll
                for (int nj = 0; nj < 4; nj++) {
                    float p = __expf(sacc[rg][nj][r] - mnew);
                    sacc[rg][nj][r] = p;
                    sum += p;
                }
                rs[r] = sum;
                lrun[rg][r] *= sc;
#pragma unroll
                for (int nj = 0; nj < 4; nj++) oacc[rg][nj][r] *= sc;
            }
#pragma unroll
            for (int d = 1; d < 16; d <<= 1)
#pragma unroll
                for (int r = 0; r < 4; r++) rs[r] += __shfl_xor(rs[r], d, 64);
#pragma unroll
            for (int r = 0; r < 4; r++) lrun[rg][r] += rs[r];
#pragma unroll
            for (int nj = 0; nj < 4; nj++)
#pragma unroll
                for (int r = 0; r < 4; r++)
                    Pl[w][rg * 16 + lg * 4 + r][nj * 16 + lr] = f2bf(sacc[rg][nj][r]);
        }
        __syncthreads();
#pragma unroll
        for (int kk = 0; kk < 2; kk++) {
            s16x8 af[2], vf[4];
#pragma unroll
            for (int rg = 0; rg < 2; rg++)
                af[rg] = *(const s16x8*)&Pl[w][rg * 16 + lr][kk * 32 + lg * 8];
#pragma unroll
            for (int nj = 0; nj < 4; nj++) {
                int d = nj * 16 + lr;
                int gs = (kk * 4 + lg) ^ (d >> 3);
                vf[nj] = *(const s16x8*)&Vt[d][gs * 8];
            }
#pragma unroll
            for (int rg = 0; rg < 2; rg++)
#pragma unroll
                for (int nj = 0; nj < 4; nj++)
                    oacc[rg][nj] = __builtin_amdgcn_mfma_f32_16x16x32_bf16(
                        af[rg], vf[nj], oacc[rg][nj], 0, 0, 0);
        }
        __syncthreads();
    }
#pragma unroll
    for (int rg = 0; rg < 2; rg++)
#pragma unroll
        for (int nj = 0; nj < 4; nj++)
#pragma unroll
            for (int r = 0; r < 4; r++) {
                int row = q0 + w * 32 + rg * 16 + lg * 4 + r;
                float v = oacc[rg][nj][r] / lrun[rg][r];
                outp[(size_t)(b * T_SEQ + row) * N_EMBD + h * HD + nj * 16 + lr] = f2bf(v);
            }
}

extern "C" void kernel_launch(void* const* d_in, const int* in_sizes, int n_in,
                              void* d_out, int out_size, void* d_ws, size_t ws_size,
                              hipStream_t stream) {
    (void)in_sizes; (void)n_in; (void)out_size; (void)ws_size;
    const float* x      = (const float*)d_in[0];
    const float* ln1_g  = (const float*)d_in[1];
    const float* ln1_b  = (const float*)d_in[2];
    const float* w_attn = (const float*)d_in[3];
    const float* b_attn = (const float*)d_in[4];
    const float* w_proj = (const float*)d_in[5];
    const float* b_proj = (const float*)d_in[6];
    const float* ln2_g  = (const float*)d_in[7];
    const float* ln2_b  = (const float*)d_in[8];
    const float* w_fc   = (const float*)d_in[9];
    const float* b_fc   = (const float*)d_in[10];
    const float* w_fc2  = (const float*)d_in[11];
    const float* b_fc2  = (const float*)d_in[12];
    float* out = (float*)d_out;
    u16* ws = (u16*)d_ws;

    u16* wTa  = ws;                                      // [2304,768]
    u16* wTp  = wTa + (size_t)2304 * 768;                // [768,768]
    u16* wTf  = wTp + (size_t)768 * 768;                 // [3072,768]
    u16* wTf2 = wTf + (size_t)3072 * 768;                // [768,3072]
    u16* hbuf = wTf2 + (size_t)768 * 3072;               // [8192,768]
    u16* abuf = hbuf + (size_t)M_TOK * N_EMBD;           // [8192,768]
    u16* big  = abuf + (size_t)M_TOK * N_EMBD;           // [8192,2304] / [8192,3072]

    wconv<<<dim3(2304 / 64, 768 / 64), 256, 0, stream>>>(w_attn, wTa, 768, 2304);
    wconv<<<dim3(768 / 64, 768 / 64), 256, 0, stream>>>(w_proj, wTp, 768, 768);
    wconv<<<dim3(3072 / 64, 768 / 64), 256, 0, stream>>>(w_fc, wTf, 768, 3072);
    wconv<<<dim3(768 / 64, 3072 / 64), 256, 0, stream>>>(w_fc2, wTf2, 3072, 768);
    ln_bf16<<<M_TOK, 256, 0, stream>>>(x, ln1_g, ln1_b, hbuf);
    gemm_bf16<0><<<dim3(18, 64), 256, 0, stream>>>(hbuf, wTa, b_attn, nullptr, big,
                                                   M_TOK, 3 * N_EMBD, N_EMBD);
    attn_mfma<<<dim3(T_SEQ / QBLK, NHEAD, BATCH), 256, 0, stream>>>(big, abuf);
    gemm_bf16<2><<<dim3(6, 64), 256, 0, stream>>>(abuf, wTp, b_proj, x, out,
                                                  M_TOK, N_EMBD, N_EMBD);
    ln_bf16<<<M_TOK, 256, 0, stream>>>(out, ln2_g, ln2_b, hbuf);
    gemm_bf16<1><<<dim3(24, 64), 256, 0, stream>>>(hbuf, wTf, b_fc, nullptr, big,
                                                   M_TOK, 4 * N_EMBD, N_EMBD);
    gemm_bf16<2><<<dim3(6, 64), 256, 0, stream>>>(big, wTf2, b_fc2, out, out,
                                                  M_TOK, N_EMBD, 4 * N_EMBD);
}

// Round 7
// 395.360 us; speedup vs baseline: 1.1980x; 1.1980x over previous
//
#include <hip/hip_runtime.h>
#include <math.h>

#define N_EMBD 768
#define T_SEQ  1024
#define BATCH  8
#define NHEAD  12
#define HD     64
#define EPS    1e-5f
#define M_TOK  (BATCH * T_SEQ)   // 8192

typedef unsigned short u16;
typedef __attribute__((ext_vector_type(8))) short          s16x8;
typedef __attribute__((ext_vector_type(8))) unsigned short u16x8;
typedef __attribute__((ext_vector_type(4))) float          f32x4;

#define GLDS(gp, lp) \
    __builtin_amdgcn_global_load_lds( \
        (const __attribute__((address_space(1))) void*)(gp), \
        (__attribute__((address_space(3))) void*)(lp), 16, 0, 0)

__device__ __forceinline__ u16 f2bf(float f) {
    unsigned int u = __float_as_uint(f);
    u += 0x7fffu + ((u >> 16) & 1u);
    return (u16)(u >> 16);
}

// ---------------- weight convert + transpose: fp32 [R][C] -> bf16 [C][R] ----------------
__global__ __launch_bounds__(256) void wconv(const float* __restrict__ in,
                                             u16* __restrict__ out, int R, int C) {
    __shared__ float tile[64][65];
    int t = threadIdx.x;
    int r0 = blockIdx.y * 64, c0 = blockIdx.x * 64;
    int rl = t >> 4, c4 = (t & 15) * 4;
#pragma unroll
    for (int i = 0; i < 4; i++) {
        float4 v = *(const float4*)(in + (size_t)(r0 + rl + i * 16) * C + c0 + c4);
        tile[rl + i * 16][c4 + 0] = v.x;
        tile[rl + i * 16][c4 + 1] = v.y;
        tile[rl + i * 16][c4 + 2] = v.z;
        tile[rl + i * 16][c4 + 3] = v.w;
    }
    __syncthreads();
#pragma unroll
    for (int i = 0; i < 4; i++) {
        int crow = rl + i * 16;
        ushort4 s4;
        s4.x = f2bf(tile[c4 + 0][crow]);
        s4.y = f2bf(tile[c4 + 1][crow]);
        s4.z = f2bf(tile[c4 + 2][crow]);
        s4.w = f2bf(tile[c4 + 3][crow]);
        *(ushort4*)(out + (size_t)(c0 + crow) * R + r0 + c4) = s4;
    }
}

// ---------------- LayerNorm fp32 in -> bf16 out ----------------
__global__ __launch_bounds__(256) void ln_bf16(const float* __restrict__ x,
                                               const float* __restrict__ g,
                                               const float* __restrict__ b,
                                               u16* __restrict__ out) {
    int row = blockIdx.x;
    int tid = threadIdx.x;
    const float* xr = x + (size_t)row * N_EMBD;
    float v0 = xr[tid], v1 = xr[tid + 256], v2 = xr[tid + 512];
    float s1 = v0 + v1 + v2;
    float s2 = v0 * v0 + v1 * v1 + v2 * v2;
    __shared__ float red1[4], red2[4];
#pragma unroll
    for (int o = 32; o > 0; o >>= 1) {
        s1 += __shfl_down(s1, o);
        s2 += __shfl_down(s2, o);
    }
    if ((tid & 63) == 0) { red1[tid >> 6] = s1; red2[tid >> 6] = s2; }
    __syncthreads();
    float mean = (red1[0] + red1[1] + red1[2] + red1[3]) * (1.0f / N_EMBD);
    float ms   = (red2[0] + red2[1] + red2[2] + red2[3]) * (1.0f / N_EMBD);
    float rs = rsqrtf(ms - mean * mean + EPS);
    u16* orow = out + (size_t)row * N_EMBD;
    orow[tid]       = f2bf((v0 - mean) * rs * g[tid]       + b[tid]);
    orow[tid + 256] = f2bf((v1 - mean) * rs * g[tid + 256] + b[tid + 256]);
    orow[tid + 512] = f2bf((v2 - mean) * rs * g[tid + 512] + b[tid + 512]);
}

// ---------------- bf16 MFMA GEMM: 2-deep dbuf, counted vmcnt (T4), XOR-swizzled LDS (T2)
// C[M,N] = A[M,K] @ Bt[N,K]^T + bias; MODE 0: bf16 out; 1: bf16 gelu; 2: fp32 +res
// LDS[row][cc] = global[row][cc ^ ((row&7)*8)]  (u16 units): achieved by pre-swizzling
// the per-lane GLOBAL col (dest stays linear, rule #21), un-swizzled on ds_read.
#define STAGE_G(buf, t)                                                              \
    do {                                                                             \
        int k0_ = (t) * 64;                                                          \
        _Pragma("unroll")                                                            \
        for (int i_ = 0; i_ < 4; i_++) {                                             \
            int c_ = i_ * 4 + w;                                                     \
            int row_ = c_ * 8 + srow;                                                \
            GLDS(A  + (size_t)(bm + row_) * K + k0_ + scolx, &As[buf][c_ * 8][0]);   \
            GLDS(Bt + (size_t)(bn + row_) * K + k0_ + scolx, &Bs[buf][c_ * 8][0]);   \
        }                                                                            \
    } while (0)

template <int MODE>
__global__ __launch_bounds__(256) void gemm_bf16(const u16* __restrict__ A,
                                                 const u16* __restrict__ Bt,
                                                 const float* __restrict__ bias,
                                                 const float* __restrict__ res,
                                                 void* __restrict__ outp,
                                                 int M, int N, int K) {
    __shared__ u16 As[2][128][64];
    __shared__ u16 Bs[2][128][64];
    int tid = threadIdx.x;
    int l = tid & 63, w = tid >> 6;
    int lr = l & 15, lg = l >> 4;
    int bm = blockIdx.y * 128, bn = blockIdx.x * 128;
    int wr = (w >> 1) * 64, wc = (w & 1) * 64;
    int srow = l >> 3;                       // 0..7 within 8-row chunk
    int scolx = ((l & 7) * 8) ^ (srow * 8);  // pre-swizzled global col (u16)
    f32x4 acc[4][4] = {};
    int nt = K / 64;
    STAGE_G(0, 0);
    STAGE_G(1, 1);
    for (int t = 0; t < nt; t++) {
        if (t < nt - 1) asm volatile("s_waitcnt vmcnt(8)" ::: "memory");
        else            asm volatile("s_waitcnt vmcnt(0)" ::: "memory");
        __builtin_amdgcn_s_barrier();       // tile t landed in all waves' chunks
        __builtin_amdgcn_sched_barrier(0);  // keep ds_reads below the wait
        int cur = t & 1;
#pragma unroll
        for (int kk = 0; kk < 2; kk++) {
            s16x8 af[4], bf[4];
            int rc = (kk * 32 + lg * 8) ^ ((lr & 7) * 8);  // un-swizzle on read
#pragma unroll
            for (int i = 0; i < 4; i++) {
                af[i] = *(const s16x8*)&As[cur][wr + i * 16 + lr][rc];
                bf[i] = *(const s16x8*)&Bs[cur][wc + i * 16 + lr][rc];
            }
#pragma unroll
            for (int mi = 0; mi < 4; mi++)
#pragma unroll
                for (int nj = 0; nj < 4; nj++)
                    acc[mi][nj] = __builtin_amdgcn_mfma_f32_16x16x32_bf16(
                        af[mi], bf[nj], acc[mi][nj], 0, 0, 0);
        }
        __builtin_amdgcn_s_barrier();       // all waves done reading buf[cur]
        if (t + 2 < nt) STAGE_G(cur, t + 2);
    }
#pragma unroll
    for (int mi = 0; mi < 4; mi++)
#pragma unroll
        for (int nj = 0; nj < 4; nj++)
#pragma unroll
            for (int r = 0; r < 4; r++) {
                int row = bm + wr + mi * 16 + lg * 4 + r;
                int col = bn + wc + nj * 16 + lr;
                float v = acc[mi][nj][r] + bias[col];
                if (MODE == 1) {
                    float u = 1.5957691216057308f * (v + 0.044715f * v * v * v);
                    v = v - v / (1.0f + __expf(u));
                }
                if (MODE == 2) {
                    v += res[(size_t)row * N + col];
                    ((float*)outp)[(size_t)row * N + col] = v;
                } else {
                    ((u16*)outp)[(size_t)row * N + col] = f2bf(v);
                }
            }
}

// ---------------- flash attention, bf16 MFMA, causal, UNSCALED ----------------
// butterfly: block handles q-tiles {bx, 7-bx} (constant 18 s-tiles); Kl XOR-swizzled
#define QBLK 128
#define SBLK 64
__global__ __launch_bounds__(256) void attn_mfma(const u16* __restrict__ qkv,
                                                 u16* __restrict__ outp) {
    __shared__ u16 Kl[SBLK][64];
    __shared__ u16 Vt[HD][72];
    __shared__ u16 Pl[4][32][72];
    int tid = threadIdx.x;
    int w = tid >> 6, l = tid & 63;
    int lr = l & 15, lg = l >> 4;
    int h = blockIdx.y, b = blockIdx.z;
    size_t bbase = (size_t)b * T_SEQ * (3 * N_EMBD);
    int srow = l >> 3;
    int scolx = ((l & 7) * 8) ^ (srow * 8);  // pre-swizzled global col for Kl

    for (int half = 0; half < 2; half++) {
        int qt = half == 0 ? blockIdx.x : 7 - blockIdx.x;
        int q0 = qt * QBLK;
        s16x8 qf[2][2];
#pragma unroll
        for (int rg = 0; rg < 2; rg++)
#pragma unroll
            for (int kk = 0; kk < 2; kk++) {
                int row = q0 + w * 32 + rg * 16 + lr;
                qf[rg][kk] = *(const s16x8*)(qkv + bbase + (size_t)row * (3 * N_EMBD) +
                                             h * HD + kk * 32 + lg * 8);
            }
        f32x4 oacc[2][4] = {};
        float mrun[2][4], lrun[2][4];
#pragma unroll
        for (int rg = 0; rg < 2; rg++)
#pragma unroll
            for (int r = 0; r < 4; r++) { mrun[rg][r] = -1e30f; lrun[rg][r] = 0.f; }

        int nt = 2 * qt + 2;
        for (int st = 0; st < nt; st++) {
            int s0 = st * SBLK;
#pragma unroll
            for (int i = 0; i < 2; i++) {
                int c = i * 4 + w;
                GLDS(qkv + bbase + (size_t)(s0 + c * 8 + srow) * (3 * N_EMBD) + N_EMBD +
                         h * HD + scolx,
                     &Kl[c * 8][0]);
            }
#pragma unroll
            for (int i = 0; i < 2; i++) {
                int c = i * 256 + tid;
                int sr = c >> 3, d0 = (c & 7) * 8;
                u16x8 vv = *(const u16x8*)(qkv + bbase + (size_t)(s0 + sr) * (3 * N_EMBD) +
                                           2 * N_EMBD + h * HD + d0);
                int sz = ((sr >> 3) ^ (d0 >> 3)) * 8 + (sr & 7);
#pragma unroll
                for (int j = 0; j < 8; j++) Vt[d0 + j][sz] = vv[j];
            }
            __syncthreads();
            f32x4 sacc[2][4] = {};
#pragma unroll
            for (int kk = 0; kk < 2; kk++) {
                s16x8 kf[4];
                int rc = (kk * 32 + lg * 8) ^ ((lr & 7) * 8);
#pragma unroll
                for (int nj = 0; nj < 4; nj++)
                    kf[nj] = *(const s16x8*)&Kl[nj * 16 + lr][rc];
#pragma unroll
                for (int rg = 0; rg < 2; rg++)
#pragma unroll
                    for (int nj = 0; nj < 4; nj++)
                        sacc[rg][nj] = __builtin_amdgcn_mfma_f32_16x16x32_bf16(
                            qf[rg][kk], kf[nj], sacc[rg][nj], 0, 0, 0);
            }
#pragma unroll
            for (int rg = 0; rg < 2; rg++) {
                int qrow0 = q0 + w * 32 + rg * 16 + lg * 4;
                float mx[4];
#pragma unroll
                for (int r = 0; r < 4; r++) {
                    int qi = qrow0 + r;
                    float mv = -1e30f;
#pragma unroll
                    for (int nj = 0; nj < 4; nj++) {
                        int si = s0 + nj * 16 + lr;
                        float v = sacc[rg][nj][r];
                        v = (si <= qi) ? v : -1e30f;
                        sacc[rg][nj][r] = v;
                        mv = fmaxf(mv, v);
                    }
                    mx[r] = mv;
                }
#pragma unroll
                for (int d = 1; d < 16; d <<= 1)
#pragma unroll
                    for (int r = 0; r < 4; r++) mx[r] = fmaxf(mx[r], __shfl_xor(mx[r], d, 64));
                float rs[4];
#pragma unroll
                for (int r = 0; r < 4; r++) {
                    float mnew = fmaxf(mrun[rg][r], mx[r]);
                    float sc = __expf(mrun[rg][r] - mnew);
                    mrun[rg][r] = mnew;
                    float sum = 0.f;
#pragma unroll
                    for (int nj = 0; nj < 4; nj++) {
                        float p = __expf(sacc[rg][nj][r] - mnew);
                        sacc[rg][nj][r] = p;
                        sum += p;
                    }
                    rs[r] = sum;
                    lrun[rg][r] *= sc;
#pragma unroll
                    for (int nj = 0; nj < 4; nj++) oacc[rg][nj][r] *= sc;
                }
#pragma unroll
                for (int d = 1; d < 16; d <<= 1)
#pragma unroll
                    for (int r = 0; r < 4; r++) rs[r] += __shfl_xor(rs[r], d, 64);
#pragma unroll
                for (int r = 0; r < 4; r++) lrun[rg][r] += rs[r];
#pragma unroll
                for (int nj = 0; nj < 4; nj++)
#pragma unroll
                    for (int r = 0; r < 4; r++)
                        Pl[w][rg * 16 + lg * 4 + r][nj * 16 + lr] = f2bf(sacc[rg][nj][r]);
            }
            __syncthreads();
#pragma unroll
            for (int kk = 0; kk < 2; kk++) {
                s16x8 af[2], vf[4];
#pragma unroll
                for (int rg = 0; rg < 2; rg++)
                    af[rg] = *(const s16x8*)&Pl[w][rg * 16 + lr][kk * 32 + lg * 8];
#pragma unroll
                for (int nj = 0; nj < 4; nj++) {
                    int d = nj * 16 + lr;
                    int gs = (kk * 4 + lg) ^ (d >> 3);
                    vf[nj] = *(const s16x8*)&Vt[d][gs * 8];
                }
#pragma unroll
                for (int rg = 0; rg < 2; rg++)
#pragma unroll
                    for (int nj = 0; nj < 4; nj++)
                        oacc[rg][nj] = __builtin_amdgcn_mfma_f32_16x16x32_bf16(
                            af[rg], vf[nj], oacc[rg][nj], 0, 0, 0);
            }
            __syncthreads();
        }
#pragma unroll
        for (int rg = 0; rg < 2; rg++)
#pragma unroll
            for (int nj = 0; nj < 4; nj++)
#pragma unroll
                for (int r = 0; r < 4; r++) {
                    int row = q0 + w * 32 + rg * 16 + lg * 4 + r;
                    float v = oacc[rg][nj][r] / lrun[rg][r];
                    outp[(size_t)(b * T_SEQ + row) * N_EMBD + h * HD + nj * 16 + lr] = f2bf(v);
                }
    }
}

extern "C" void kernel_launch(void* const* d_in, const int* in_sizes, int n_in,
                              void* d_out, int out_size, void* d_ws, size_t ws_size,
                              hipStream_t stream) {
    (void)in_sizes; (void)n_in; (void)out_size; (void)ws_size;
    const float* x      = (const float*)d_in[0];
    const float* ln1_g  = (const float*)d_in[1];
    const float* ln1_b  = (const float*)d_in[2];
    const float* w_attn = (const float*)d_in[3];
    const float* b_attn = (const float*)d_in[4];
    const float* w_proj = (const float*)d_in[5];
    const float* b_proj = (const float*)d_in[6];
    const float* ln2_g  = (const float*)d_in[7];
    const float* ln2_b  = (const float*)d_in[8];
    const float* w_fc   = (const float*)d_in[9];
    const float* b_fc   = (const float*)d_in[10];
    const float* w_fc2  = (const float*)d_in[11];
    const float* b_fc2  = (const float*)d_in[12];
    float* out = (float*)d_out;
    u16* ws = (u16*)d_ws;

    u16* wTa  = ws;                                      // [2304,768]
    u16* wTp  = wTa + (size_t)2304 * 768;                // [768,768]
    u16* wTf  = wTp + (size_t)768 * 768;                 // [3072,768]
    u16* wTf2 = wTf + (size_t)3072 * 768;                // [768,3072]
    u16* hbuf = wTf2 + (size_t)768 * 3072;               // [8192,768]
    u16* abuf = hbuf + (size_t)M_TOK * N_EMBD;           // [8192,768]
    u16* big  = abuf + (size_t)M_TOK * N_EMBD;           // [8192,2304] / [8192,3072]

    wconv<<<dim3(2304 / 64, 768 / 64), 256, 0, stream>>>(w_attn, wTa, 768, 2304);
    wconv<<<dim3(768 / 64, 768 / 64), 256, 0, stream>>>(w_proj, wTp, 768, 768);
    wconv<<<dim3(3072 / 64, 768 / 64), 256, 0, stream>>>(w_fc, wTf, 768, 3072);
    wconv<<<dim3(768 / 64, 3072 / 64), 256, 0, stream>>>(w_fc2, wTf2, 3072, 768);
    ln_bf16<<<M_TOK, 256, 0, stream>>>(x, ln1_g, ln1_b, hbuf);
    gemm_bf16<0><<<dim3(18, 64), 256, 0, stream>>>(hbuf, wTa, b_attn, nullptr, big,
                                                   M_TOK, 3 * N_EMBD, N_EMBD);
    attn_mfma<<<dim3(T_SEQ / QBLK / 2, NHEAD, BATCH), 256, 0, stream>>>(big, abuf);
    gemm_bf16<2><<<dim3(6, 64), 256, 0, stream>>>(abuf, wTp, b_proj, x, out,
                                                  M_TOK, N_EMBD, N_EMBD);
    ln_bf16<<<M_TOK, 256, 0, stream>>>(out, ln2_g, ln2_b, hbuf);
    gemm_bf16<1><<<dim3(24, 64), 256, 0, stream>>>(hbuf, wTf, b_fc, nullptr, big,
                                                   M_TOK, 4 * N_EMBD, N_EMBD);
    gemm_bf16<2><<<dim3(6, 64), 256, 0, stream>>>(big, wTf2, b_fc2, out, out,
                                                  M_TOK, N_EMBD, 4 * N_EMBD);
}

// Round 8
// 373.461 us; speedup vs baseline: 1.2682x; 1.0586x over previous
//
#include <hip/hip_runtime.h>
#include <math.h>

#define N_EMBD 768
#define T_SEQ  1024
#define BATCH  8
#define NHEAD  12
#define HD     64
#define EPS    1e-5f
#define M_TOK  (BATCH * T_SEQ)   // 8192

typedef unsigned short u16;
typedef __attribute__((ext_vector_type(8))) short          s16x8;
typedef __attribute__((ext_vector_type(8))) unsigned short u16x8;
typedef __attribute__((ext_vector_type(4))) float          f32x4;

#define GLDS(gp, lp) \
    __builtin_amdgcn_global_load_lds( \
        (const __attribute__((address_space(1))) void*)(gp), \
        (__attribute__((address_space(3))) void*)(lp), 16, 0, 0)

__device__ __forceinline__ u16 f2bf(float f) {
    unsigned int u = __float_as_uint(f);
    u += 0x7fffu + ((u >> 16) & 1u);
    return (u16)(u >> 16);
}

// ---------------- weight convert + transpose: fp32 [R][C] -> bf16 [C][R] ----------------
__global__ __launch_bounds__(256) void wconv(const float* __restrict__ in,
                                             u16* __restrict__ out, int R, int C) {
    __shared__ float tile[64][65];
    int t = threadIdx.x;
    int r0 = blockIdx.y * 64, c0 = blockIdx.x * 64;
    int rl = t >> 4, c4 = (t & 15) * 4;
#pragma unroll
    for (int i = 0; i < 4; i++) {
        float4 v = *(const float4*)(in + (size_t)(r0 + rl + i * 16) * C + c0 + c4);
        tile[rl + i * 16][c4 + 0] = v.x;
        tile[rl + i * 16][c4 + 1] = v.y;
        tile[rl + i * 16][c4 + 2] = v.z;
        tile[rl + i * 16][c4 + 3] = v.w;
    }
    __syncthreads();
#pragma unroll
    for (int i = 0; i < 4; i++) {
        int crow = rl + i * 16;
        ushort4 s4;
        s4.x = f2bf(tile[c4 + 0][crow]);
        s4.y = f2bf(tile[c4 + 1][crow]);
        s4.z = f2bf(tile[c4 + 2][crow]);
        s4.w = f2bf(tile[c4 + 3][crow]);
        *(ushort4*)(out + (size_t)(c0 + crow) * R + r0 + c4) = s4;
    }
}

// ---------------- LayerNorm fp32 in -> bf16 out ----------------
__global__ __launch_bounds__(256) void ln_bf16(const float* __restrict__ x,
                                               const float* __restrict__ g,
                                               const float* __restrict__ b,
                                               u16* __restrict__ out) {
    int row = blockIdx.x;
    int tid = threadIdx.x;
    const float* xr = x + (size_t)row * N_EMBD;
    float v0 = xr[tid], v1 = xr[tid + 256], v2 = xr[tid + 512];
    float s1 = v0 + v1 + v2;
    float s2 = v0 * v0 + v1 * v1 + v2 * v2;
    __shared__ float red1[4], red2[4];
#pragma unroll
    for (int o = 32; o > 0; o >>= 1) {
        s1 += __shfl_down(s1, o);
        s2 += __shfl_down(s2, o);
    }
    if ((tid & 63) == 0) { red1[tid >> 6] = s1; red2[tid >> 6] = s2; }
    __syncthreads();
    float mean = (red1[0] + red1[1] + red1[2] + red1[3]) * (1.0f / N_EMBD);
    float ms   = (red2[0] + red2[1] + red2[2] + red2[3]) * (1.0f / N_EMBD);
    float rs = rsqrtf(ms - mean * mean + EPS);
    u16* orow = out + (size_t)row * N_EMBD;
    orow[tid]       = f2bf((v0 - mean) * rs * g[tid]       + b[tid]);
    orow[tid + 256] = f2bf((v1 - mean) * rs * g[tid + 256] + b[tid + 256]);
    orow[tid + 512] = f2bf((v2 - mean) * rs * g[tid + 512] + b[tid + 512]);
}

// ---------------- bf16 MFMA GEMM: 2-deep dbuf, counted vmcnt (T4), XOR-swizzled LDS (T2)
// C[M,N] = A[M,K] @ Bt[N,K]^T + bias; MODE 0: bf16 out; 1: bf16 gelu; 2: fp32 +res
#define STAGE_G(buf, t)                                                              \
    do {                                                                             \
        int k0_ = (t) * 64;                                                          \
        _Pragma("unroll")                                                            \
        for (int i_ = 0; i_ < 4; i_++) {                                             \
            int c_ = i_ * 4 + w;                                                     \
            int row_ = c_ * 8 + srow;                                                \
            GLDS(A  + (size_t)(bm + row_) * K + k0_ + scolx, &As[buf][c_ * 8][0]);   \
            GLDS(Bt + (size_t)(bn + row_) * K + k0_ + scolx, &Bs[buf][c_ * 8][0]);   \
        }                                                                            \
    } while (0)

template <int MODE>
__global__ __launch_bounds__(256) void gemm_bf16(const u16* __restrict__ A,
                                                 const u16* __restrict__ Bt,
                                                 const float* __restrict__ bias,
                                                 const float* __restrict__ res,
                                                 void* __restrict__ outp,
                                                 int M, int N, int K) {
    __shared__ u16 As[2][128][64];
    __shared__ u16 Bs[2][128][64];
    int tid = threadIdx.x;
    int l = tid & 63, w = tid >> 6;
    int lr = l & 15, lg = l >> 4;
    int bm = blockIdx.y * 128, bn = blockIdx.x * 128;
    int wr = (w >> 1) * 64, wc = (w & 1) * 64;
    int srow = l >> 3;                       // 0..7 within 8-row chunk
    int scolx = ((l & 7) * 8) ^ (srow * 8);  // pre-swizzled global col (u16)
    f32x4 acc[4][4] = {};
    int nt = K / 64;
    STAGE_G(0, 0);
    STAGE_G(1, 1);
    for (int t = 0; t < nt; t++) {
        if (t < nt - 1) asm volatile("s_waitcnt vmcnt(8)" ::: "memory");
        else            asm volatile("s_waitcnt vmcnt(0)" ::: "memory");
        __builtin_amdgcn_s_barrier();       // tile t landed in all waves' chunks
        __builtin_amdgcn_sched_barrier(0);  // keep ds_reads below the wait
        int cur = t & 1;
#pragma unroll
        for (int kk = 0; kk < 2; kk++) {
            s16x8 af[4], bf[4];
            int rc = (kk * 32 + lg * 8) ^ ((lr & 7) * 8);  // un-swizzle on read
#pragma unroll
            for (int i = 0; i < 4; i++) {
                af[i] = *(const s16x8*)&As[cur][wr + i * 16 + lr][rc];
                bf[i] = *(const s16x8*)&Bs[cur][wc + i * 16 + lr][rc];
            }
            __builtin_amdgcn_s_setprio(1);
#pragma unroll
            for (int mi = 0; mi < 4; mi++)
#pragma unroll
                for (int nj = 0; nj < 4; nj++)
                    acc[mi][nj] = __builtin_amdgcn_mfma_f32_16x16x32_bf16(
                        af[mi], bf[nj], acc[mi][nj], 0, 0, 0);
            __builtin_amdgcn_s_setprio(0);
        }
        __builtin_amdgcn_s_barrier();       // all waves done reading buf[cur]
        if (t + 2 < nt) STAGE_G(cur, t + 2);
    }
#pragma unroll
    for (int mi = 0; mi < 4; mi++)
#pragma unroll
        for (int nj = 0; nj < 4; nj++)
#pragma unroll
            for (int r = 0; r < 4; r++) {
                int row = bm + wr + mi * 16 + lg * 4 + r;
                int col = bn + wc + nj * 16 + lr;
                float v = acc[mi][nj][r] + bias[col];
                if (MODE == 1) {
                    float u = 1.5957691216057308f * (v + 0.044715f * v * v * v);
                    v = v - v / (1.0f + __expf(u));
                }
                if (MODE == 2) {
                    v += res[(size_t)row * N + col];
                    ((float*)outp)[(size_t)row * N + col] = v;
                } else {
                    ((u16*)outp)[(size_t)row * N + col] = f2bf(v);
                }
            }
}

// ---------------- flash attention, bf16 MFMA, causal, UNSCALED ----------------
// QBLK=64: 16 q-tiles/(b,h); butterfly pair {bx, 15-bx} -> 768 blocks, 17 s-tiles each
#define QBLK 64
#define SBLK 64
__global__ __launch_bounds__(256) void attn_mfma(const u16* __restrict__ qkv,
                                                 u16* __restrict__ outp) {
    __shared__ u16 Kl[SBLK][64];   // XOR-swizzled via pre-swizzled global col
    __shared__ u16 Vt[HD][72];     // V^T, pitch 72 + XOR swizzle on s-group
    __shared__ u16 Pl[4][16][72];  // per-wave P tile (16 q-rows)
    int tid = threadIdx.x;
    int w = tid >> 6, l = tid & 63;
    int lr = l & 15, lg = l >> 4;
    int h = blockIdx.y, b = blockIdx.z;
    size_t bbase = (size_t)b * T_SEQ * (3 * N_EMBD);
    int srow = l >> 3;
    int scolx = ((l & 7) * 8) ^ (srow * 8);  // pre-swizzled global col for Kl

    for (int half = 0; half < 2; half++) {
        int qt = half == 0 ? blockIdx.x : 15 - blockIdx.x;
        int q0 = qt * QBLK;
        // Q fragments (wave owns 16 q-rows)
        s16x8 qf[2];
#pragma unroll
        for (int kk = 0; kk < 2; kk++) {
            int row = q0 + w * 16 + lr;
            qf[kk] = *(const s16x8*)(qkv + bbase + (size_t)row * (3 * N_EMBD) +
                                     h * HD + kk * 32 + lg * 8);
        }
        f32x4 oacc[4] = {};
        float mrun[4], lrun[4];
#pragma unroll
        for (int r = 0; r < 4; r++) { mrun[r] = -1e30f; lrun[r] = 0.f; }

        int nt = qt + 1;
        for (int st = 0; st < nt; st++) {
            int s0 = st * SBLK;
#pragma unroll
            for (int i = 0; i < 2; i++) {
                int c = i * 4 + w;
                GLDS(qkv + bbase + (size_t)(s0 + c * 8 + srow) * (3 * N_EMBD) + N_EMBD +
                         h * HD + scolx,
                     &Kl[c * 8][0]);
            }
#pragma unroll
            for (int i = 0; i < 2; i++) {
                int c = i * 256 + tid;
                int sr = c >> 3, d0 = (c & 7) * 8;
                u16x8 vv = *(const u16x8*)(qkv + bbase + (size_t)(s0 + sr) * (3 * N_EMBD) +
                                           2 * N_EMBD + h * HD + d0);
                int sz = ((sr >> 3) ^ (d0 >> 3)) * 8 + (sr & 7);
#pragma unroll
                for (int j = 0; j < 8; j++) Vt[d0 + j][sz] = vv[j];
            }
            __syncthreads();
            // ---- S = Q @ K^T ----
            f32x4 sacc[4] = {};
#pragma unroll
            for (int kk = 0; kk < 2; kk++) {
                s16x8 kf[4];
                int rc = (kk * 32 + lg * 8) ^ ((lr & 7) * 8);
#pragma unroll
                for (int nj = 0; nj < 4; nj++)
                    kf[nj] = *(const s16x8*)&Kl[nj * 16 + lr][rc];
                __builtin_amdgcn_s_setprio(1);
#pragma unroll
                for (int nj = 0; nj < 4; nj++)
                    sacc[nj] = __builtin_amdgcn_mfma_f32_16x16x32_bf16(
                        qf[kk], kf[nj], sacc[nj], 0, 0, 0);
                __builtin_amdgcn_s_setprio(0);
            }
            // ---- mask + online softmax (fp32) + P -> LDS (bf16) ----
            {
                int qrow0 = q0 + w * 16 + lg * 4;
                float mx[4];
#pragma unroll
                for (int r = 0; r < 4; r++) {
                    int qi = qrow0 + r;
                    float mv = -1e30f;
#pragma unroll
                    for (int nj = 0; nj < 4; nj++) {
                        int si = s0 + nj * 16 + lr;
                        float v = sacc[nj][r];
                        v = (si <= qi) ? v : -1e30f;
                        sacc[nj][r] = v;
                        mv = fmaxf(mv, v);
                    }
                    mx[r] = mv;
                }
#pragma unroll
                for (int d = 1; d < 16; d <<= 1)
#pragma unroll
                    for (int r = 0; r < 4; r++) mx[r] = fmaxf(mx[r], __shfl_xor(mx[r], d, 64));
                float rs[4];
#pragma unroll
                for (int r = 0; r < 4; r++) {
                    float mnew = fmaxf(mrun[r], mx[r]);
                    float sc = __expf(mrun[r] - mnew);
                    mrun[r] = mnew;
                    float sum = 0.f;
#pragma unroll
                    for (int nj = 0; nj < 4; nj++) {
                        float p = __expf(sacc[nj][r] - mnew);
                        sacc[nj][r] = p;
                        sum += p;
                    }
                    rs[r] = sum;
                    lrun[r] *= sc;
#pragma unroll
                    for (int nj = 0; nj < 4; nj++) oacc[nj][r] *= sc;
                }
#pragma unroll
                for (int d = 1; d < 16; d <<= 1)
#pragma unroll
                    for (int r = 0; r < 4; r++) rs[r] += __shfl_xor(rs[r], d, 64);
#pragma unroll
                for (int r = 0; r < 4; r++) lrun[r] += rs[r];
#pragma unroll
                for (int nj = 0; nj < 4; nj++)
#pragma unroll
                    for (int r = 0; r < 4; r++)
                        Pl[w][lg * 4 + r][nj * 16 + lr] = f2bf(sacc[nj][r]);
            }
            __syncthreads();
            // ---- O += P @ V ----
#pragma unroll
            for (int kk = 0; kk < 2; kk++) {
                s16x8 af, vf[4];
                af = *(const s16x8*)&Pl[w][lr][kk * 32 + lg * 8];
#pragma unroll
                for (int nj = 0; nj < 4; nj++) {
                    int d = nj * 16 + lr;
                    int gs = (kk * 4 + lg) ^ (d >> 3);
                    vf[nj] = *(const s16x8*)&Vt[d][gs * 8];
                }
                __builtin_amdgcn_s_setprio(1);
#pragma unroll
                for (int nj = 0; nj < 4; nj++)
                    oacc[nj] = __builtin_amdgcn_mfma_f32_16x16x32_bf16(
                        af, vf[nj], oacc[nj], 0, 0, 0);
                __builtin_amdgcn_s_setprio(0);
            }
            __syncthreads();
        }
        // ---- write O/l as bf16 ----
#pragma unroll
        for (int nj = 0; nj < 4; nj++)
#pragma unroll
            for (int r = 0; r < 4; r++) {
                int row = q0 + w * 16 + lg * 4 + r;
                float v = oacc[nj][r] / lrun[r];
                outp[(size_t)(b * T_SEQ + row) * N_EMBD + h * HD + nj * 16 + lr] = f2bf(v);
            }
    }
}

extern "C" void kernel_launch(void* const* d_in, const int* in_sizes, int n_in,
                              void* d_out, int out_size, void* d_ws, size_t ws_size,
                              hipStream_t stream) {
    (void)in_sizes; (void)n_in; (void)out_size; (void)ws_size;
    const float* x      = (const float*)d_in[0];
    const float* ln1_g  = (const float*)d_in[1];
    const float* ln1_b  = (const float*)d_in[2];
    const float* w_attn = (const float*)d_in[3];
    const float* b_attn = (const float*)d_in[4];
    const float* w_proj = (const float*)d_in[5];
    const float* b_proj = (const float*)d_in[6];
    const float* ln2_g  = (const float*)d_in[7];
    const float* ln2_b  = (const float*)d_in[8];
    const float* w_fc   = (const float*)d_in[9];
    const float* b_fc   = (const float*)d_in[10];
    const float* w_fc2  = (const float*)d_in[11];
    const float* b_fc2  = (const float*)d_in[12];
    float* out = (float*)d_out;
    u16* ws = (u16*)d_ws;

    u16* wTa  = ws;                                      // [2304,768]
    u16* wTp  = wTa + (size_t)2304 * 768;                // [768,768]
    u16* wTf  = wTp + (size_t)768 * 768;                 // [3072,768]
    u16* wTf2 = wTf + (size_t)3072 * 768;                // [768,3072]
    u16* hbuf = wTf2 + (size_t)768 * 3072;               // [8192,768]
    u16* abuf = hbuf + (size_t)M_TOK * N_EMBD;           // [8192,768]
    u16* big  = abuf + (size_t)M_TOK * N_EMBD;           // [8192,2304] / [8192,3072]

    wconv<<<dim3(2304 / 64, 768 / 64), 256, 0, stream>>>(w_attn, wTa, 768, 2304);
    wconv<<<dim3(768 / 64, 768 / 64), 256, 0, stream>>>(w_proj, wTp, 768, 768);
    wconv<<<dim3(3072 / 64, 768 / 64), 256, 0, stream>>>(w_fc, wTf, 768, 3072);
    wconv<<<dim3(768 / 64, 3072 / 64), 256, 0, stream>>>(w_fc2, wTf2, 3072, 768);
    ln_bf16<<<M_TOK, 256, 0, stream>>>(x, ln1_g, ln1_b, hbuf);
    gemm_bf16<0><<<dim3(18, 64), 256, 0, stream>>>(hbuf, wTa, b_attn, nullptr, big,
                                                   M_TOK, 3 * N_EMBD, N_EMBD);
    attn_mfma<<<dim3(T_SEQ / QBLK / 2, NHEAD, BATCH), 256, 0, stream>>>(big, abuf);
    gemm_bf16<2><<<dim3(6, 64), 256, 0, stream>>>(abuf, wTp, b_proj, x, out,
                                                  M_TOK, N_EMBD, N_EMBD);
    ln_bf16<<<M_TOK, 256, 0, stream>>>(out, ln2_g, ln2_b, hbuf);
    gemm_bf16<1><<<dim3(24, 64), 256, 0, stream>>>(hbuf, wTf, b_fc, nullptr, big,
                                                   M_TOK, 4 * N_EMBD, N_EMBD);
    gemm_bf16<2><<<dim3(6, 64), 256, 0, stream>>>(big, wTf2, b_fc2, out, out,
                                                  M_TOK, N_EMBD, 4 * N_EMBD);
}

// Round 9
// 370.268 us; speedup vs baseline: 1.2792x; 1.0086x over previous
//
#include <hip/hip_runtime.h>
#include <math.h>

#define N_EMBD 768
#define T_SEQ  1024
#define BATCH  8
#define NHEAD  12
#define HD     64
#define EPS    1e-5f
#define M_TOK  (BATCH * T_SEQ)   // 8192

typedef unsigned short u16;
typedef __attribute__((ext_vector_type(8))) short          s16x8;
typedef __attribute__((ext_vector_type(8))) unsigned short u16x8;
typedef __attribute__((ext_vector_type(4))) float          f32x4;

#define GLDS(gp, lp) \
    __builtin_amdgcn_global_load_lds( \
        (const __attribute__((address_space(1))) void*)(gp), \
        (__attribute__((address_space(3))) void*)(lp), 16, 0, 0)

__device__ __forceinline__ u16 f2bf(float f) {
    unsigned int u = __float_as_uint(f);
    u += 0x7fffu + ((u >> 16) & 1u);
    return (u16)(u >> 16);
}

// ---------------- weight convert + transpose: fp32 [R][C] -> bf16 [C][R] ----------------
__global__ __launch_bounds__(256) void wconv(const float* __restrict__ in,
                                             u16* __restrict__ out, int R, int C) {
    __shared__ float tile[64][65];
    int t = threadIdx.x;
    int r0 = blockIdx.y * 64, c0 = blockIdx.x * 64;
    int rl = t >> 4, c4 = (t & 15) * 4;
#pragma unroll
    for (int i = 0; i < 4; i++) {
        float4 v = *(const float4*)(in + (size_t)(r0 + rl + i * 16) * C + c0 + c4);
        tile[rl + i * 16][c4 + 0] = v.x;
        tile[rl + i * 16][c4 + 1] = v.y;
        tile[rl + i * 16][c4 + 2] = v.z;
        tile[rl + i * 16][c4 + 3] = v.w;
    }
    __syncthreads();
#pragma unroll
    for (int i = 0; i < 4; i++) {
        int crow = rl + i * 16;
        ushort4 s4;
        s4.x = f2bf(tile[c4 + 0][crow]);
        s4.y = f2bf(tile[c4 + 1][crow]);
        s4.z = f2bf(tile[c4 + 2][crow]);
        s4.w = f2bf(tile[c4 + 3][crow]);
        *(ushort4*)(out + (size_t)(c0 + crow) * R + r0 + c4) = s4;
    }
}

// ---------------- LayerNorm fp32 in -> bf16 out ----------------
__global__ __launch_bounds__(256) void ln_bf16(const float* __restrict__ x,
                                               const float* __restrict__ g,
                                               const float* __restrict__ b,
                                               u16* __restrict__ out) {
    int row = blockIdx.x;
    int tid = threadIdx.x;
    const float* xr = x + (size_t)row * N_EMBD;
    float v0 = xr[tid], v1 = xr[tid + 256], v2 = xr[tid + 512];
    float s1 = v0 + v1 + v2;
    float s2 = v0 * v0 + v1 * v1 + v2 * v2;
    __shared__ float red1[4], red2[4];
#pragma unroll
    for (int o = 32; o > 0; o >>= 1) {
        s1 += __shfl_down(s1, o);
        s2 += __shfl_down(s2, o);
    }
    if ((tid & 63) == 0) { red1[tid >> 6] = s1; red2[tid >> 6] = s2; }
    __syncthreads();
    float mean = (red1[0] + red1[1] + red1[2] + red1[3]) * (1.0f / N_EMBD);
    float ms   = (red2[0] + red2[1] + red2[2] + red2[3]) * (1.0f / N_EMBD);
    float rs = rsqrtf(ms - mean * mean + EPS);
    u16* orow = out + (size_t)row * N_EMBD;
    orow[tid]       = f2bf((v0 - mean) * rs * g[tid]       + b[tid]);
    orow[tid + 256] = f2bf((v1 - mean) * rs * g[tid + 256] + b[tid + 256]);
    orow[tid + 512] = f2bf((v2 - mean) * rs * g[tid + 512] + b[tid + 512]);
}

// ---------------- bf16 MFMA GEMM: compile-time K, unrolled, 2-deep counted vmcnt ------
// C[M,N] = A[M,K] @ Bt[N,K]^T + bias; MODE 0: bf16 out; 1: bf16 gelu; 2: fp32 +res
// BMT=128: 128x128 tile, 4 waves of 64x64, 8 glds/stage  -> vmcnt(8)
// BMT=64 :  64x128 tile, 4 waves of 64x32, 6 glds/stage  -> vmcnt(6)
template <int MODE, int KK, int BMT>
__global__ __launch_bounds__(256) void gemm_bf16(const u16* __restrict__ A,
                                                 const u16* __restrict__ Bt,
                                                 const float* __restrict__ bias,
                                                 const float* __restrict__ res,
                                                 void* __restrict__ outp,
                                                 int M, int N) {
    constexpr int NT = KK / 64;
    constexpr int NJ = (BMT == 128) ? 4 : 2;
    __shared__ u16 As[2][BMT][64];
    __shared__ u16 Bs[2][128][64];
    int tid = threadIdx.x;
    int l = tid & 63, w = tid >> 6;
    int lr = l & 15, lg = l >> 4;
    int bm = blockIdx.y * BMT, bn = blockIdx.x * 128;
    int wr = (BMT == 128) ? (w >> 1) * 64 : 0;
    int wc = (BMT == 128) ? (w & 1) * 64 : w * 32;
    int srow = l >> 3;                       // 0..7 within 8-row chunk
    int scolx = ((l & 7) * 8) ^ (srow * 8);  // pre-swizzled global col (u16)

    auto stage = [&](int buf, int t) {
        int k0 = t * 64;
        if constexpr (BMT == 128) {
#pragma unroll
            for (int i = 0; i < 4; i++) {
                int c = i * 4 + w;
                int row = c * 8 + srow;
                GLDS(A  + (size_t)(bm + row) * KK + k0 + scolx, &As[buf][c * 8][0]);
                GLDS(Bt + (size_t)(bn + row) * KK + k0 + scolx, &Bs[buf][c * 8][0]);
            }
        } else {
#pragma unroll
            for (int i = 0; i < 2; i++) {
                int c = i * 4 + w;
                GLDS(A + (size_t)(bm + c * 8 + srow) * KK + k0 + scolx, &As[buf][c * 8][0]);
            }
#pragma unroll
            for (int i = 0; i < 4; i++) {
                int c = i * 4 + w;
                GLDS(Bt + (size_t)(bn + c * 8 + srow) * KK + k0 + scolx, &Bs[buf][c * 8][0]);
            }
        }
    };

    f32x4 acc[4][NJ] = {};
    stage(0, 0);
    stage(1, 1);
#pragma unroll
    for (int t = 0; t < NT; t++) {
        if (t < NT - 1) {
            if constexpr (BMT == 128) asm volatile("s_waitcnt vmcnt(8)" ::: "memory");
            else                      asm volatile("s_waitcnt vmcnt(6)" ::: "memory");
        } else {
            asm volatile("s_waitcnt vmcnt(0)" ::: "memory");
        }
        __builtin_amdgcn_s_barrier();       // tile t landed in all waves' chunks
        __builtin_amdgcn_sched_barrier(0);  // keep ds_reads below the wait
        int cur = t & 1;
#pragma unroll
        for (int kk = 0; kk < 2; kk++) {
            s16x8 af[4], bf[NJ];
            int rc = (kk * 32 + lg * 8) ^ ((lr & 7) * 8);  // un-swizzle on read
#pragma unroll
            for (int i = 0; i < 4; i++)
                af[i] = *(const s16x8*)&As[cur][wr + i * 16 + lr][rc];
#pragma unroll
            for (int j = 0; j < NJ; j++)
                bf[j] = *(const s16x8*)&Bs[cur][wc + j * 16 + lr][rc];
            __builtin_amdgcn_s_setprio(1);
#pragma unroll
            for (int mi = 0; mi < 4; mi++)
#pragma unroll
                for (int nj = 0; nj < NJ; nj++)
                    acc[mi][nj] = __builtin_amdgcn_mfma_f32_16x16x32_bf16(
                        af[mi], bf[nj], acc[mi][nj], 0, 0, 0);
            __builtin_amdgcn_s_setprio(0);
        }
        __builtin_amdgcn_s_barrier();       // all waves done reading buf[cur]
        if (t + 2 < NT) stage(cur, t + 2);
    }
#pragma unroll
    for (int mi = 0; mi < 4; mi++)
#pragma unroll
        for (int nj = 0; nj < NJ; nj++)
#pragma unroll
            for (int r = 0; r < 4; r++) {
                int row = bm + wr + mi * 16 + lg * 4 + r;
                int col = bn + wc + nj * 16 + lr;
                float v = acc[mi][nj][r] + bias[col];
                if (MODE == 1) {
                    float u = 1.5957691216057308f * (v + 0.044715f * v * v * v);
                    v = v - v / (1.0f + __expf(u));
                }
                if (MODE == 2) {
                    v += res[(size_t)row * N + col];
                    ((float*)outp)[(size_t)row * N + col] = v;
                } else {
                    ((u16*)outp)[(size_t)row * N + col] = f2bf(v);
                }
            }
}

// ---------------- flash attention, bf16 MFMA, causal, UNSCALED (r8, unchanged) --------
// QBLK=64: 16 q-tiles/(b,h); butterfly pair {bx, 15-bx} -> 768 blocks, 17 s-tiles each
#define QBLK 64
#define SBLK 64
__global__ __launch_bounds__(256) void attn_mfma(const u16* __restrict__ qkv,
                                                 u16* __restrict__ outp) {
    __shared__ u16 Kl[SBLK][64];   // XOR-swizzled via pre-swizzled global col
    __shared__ u16 Vt[HD][72];     // V^T, pitch 72 + XOR swizzle on s-group
    __shared__ u16 Pl[4][16][72];  // per-wave P tile (16 q-rows)
    int tid = threadIdx.x;
    int w = tid >> 6, l = tid & 63;
    int lr = l & 15, lg = l >> 4;
    int h = blockIdx.y, b = blockIdx.z;
    size_t bbase = (size_t)b * T_SEQ * (3 * N_EMBD);
    int srow = l >> 3;
    int scolx = ((l & 7) * 8) ^ (srow * 8);  // pre-swizzled global col for Kl

    for (int half = 0; half < 2; half++) {
        int qt = half == 0 ? blockIdx.x : 15 - blockIdx.x;
        int q0 = qt * QBLK;
        s16x8 qf[2];
#pragma unroll
        for (int kk = 0; kk < 2; kk++) {
            int row = q0 + w * 16 + lr;
            qf[kk] = *(const s16x8*)(qkv + bbase + (size_t)row * (3 * N_EMBD) +
                                     h * HD + kk * 32 + lg * 8);
        }
        f32x4 oacc[4] = {};
        float mrun[4], lrun[4];
#pragma unroll
        for (int r = 0; r < 4; r++) { mrun[r] = -1e30f; lrun[r] = 0.f; }

        int nt = qt + 1;
        for (int st = 0; st < nt; st++) {
            int s0 = st * SBLK;
#pragma unroll
            for (int i = 0; i < 2; i++) {
                int c = i * 4 + w;
                GLDS(qkv + bbase + (size_t)(s0 + c * 8 + srow) * (3 * N_EMBD) + N_EMBD +
                         h * HD + scolx,
                     &Kl[c * 8][0]);
            }
#pragma unroll
            for (int i = 0; i < 2; i++) {
                int c = i * 256 + tid;
                int sr = c >> 3, d0 = (c & 7) * 8;
                u16x8 vv = *(const u16x8*)(qkv + bbase + (size_t)(s0 + sr) * (3 * N_EMBD) +
                                           2 * N_EMBD + h * HD + d0);
                int sz = ((sr >> 3) ^ (d0 >> 3)) * 8 + (sr & 7);
#pragma unroll
                for (int j = 0; j < 8; j++) Vt[d0 + j][sz] = vv[j];
            }
            __syncthreads();
            f32x4 sacc[4] = {};
#pragma unroll
            for (int kk = 0; kk < 2; kk++) {
                s16x8 kf[4];
                int rc = (kk * 32 + lg * 8) ^ ((lr & 7) * 8);
#pragma unroll
                for (int nj = 0; nj < 4; nj++)
                    kf[nj] = *(const s16x8*)&Kl[nj * 16 + lr][rc];
                __builtin_amdgcn_s_setprio(1);
#pragma unroll
                for (int nj = 0; nj < 4; nj++)
                    sacc[nj] = __builtin_amdgcn_mfma_f32_16x16x32_bf16(
                        qf[kk], kf[nj], sacc[nj], 0, 0, 0);
                __builtin_amdgcn_s_setprio(0);
            }
            {
                int qrow0 = q0 + w * 16 + lg * 4;
                float mx[4];
#pragma unroll
                for (int r = 0; r < 4; r++) {
                    int qi = qrow0 + r;
                    float mv = -1e30f;
#pragma unroll
                    for (int nj = 0; nj < 4; nj++) {
                        int si = s0 + nj * 16 + lr;
                        float v = sacc[nj][r];
                        v = (si <= qi) ? v : -1e30f;
                        sacc[nj][r] = v;
                        mv = fmaxf(mv, v);
                    }
                    mx[r] = mv;
                }
#pragma unroll
                for (int d = 1; d < 16; d <<= 1)
#pragma unroll
                    for (int r = 0; r < 4; r++) mx[r] = fmaxf(mx[r], __shfl_xor(mx[r], d, 64));
                float rs[4];
#pragma unroll
                for (int r = 0; r < 4; r++) {
                    float mnew = fmaxf(mrun[r], mx[r]);
                    float sc = __expf(mrun[r] - mnew);
                    mrun[r] = mnew;
                    float sum = 0.f;
#pragma unroll
                    for (int nj = 0; nj < 4; nj++) {
                        float p = __expf(sacc[nj][r] - mnew);
                        sacc[nj][r] = p;
                        sum += p;
                    }
                    rs[r] = sum;
                    lrun[r] *= sc;
#pragma unroll
                    for (int nj = 0; nj < 4; nj++) oacc[nj][r] *= sc;
                }
#pragma unroll
                for (int d = 1; d < 16; d <<= 1)
#pragma unroll
                    for (int r = 0; r < 4; r++) rs[r] += __shfl_xor(rs[r], d, 64);
#pragma unroll
                for (int r = 0; r < 4; r++) lrun[r] += rs[r];
#pragma unroll
                for (int nj = 0; nj < 4; nj++)
#pragma unroll
                    for (int r = 0; r < 4; r++)
                        Pl[w][lg * 4 + r][nj * 16 + lr] = f2bf(sacc[nj][r]);
            }
            __syncthreads();
#pragma unroll
            for (int kk = 0; kk < 2; kk++) {
                s16x8 af, vf[4];
                af = *(const s16x8*)&Pl[w][lr][kk * 32 + lg * 8];
#pragma unroll
                for (int nj = 0; nj < 4; nj++) {
                    int d = nj * 16 + lr;
                    int gs = (kk * 4 + lg) ^ (d >> 3);
                    vf[nj] = *(const s16x8*)&Vt[d][gs * 8];
                }
                __builtin_amdgcn_s_setprio(1);
#pragma unroll
                for (int nj = 0; nj < 4; nj++)
                    oacc[nj] = __builtin_amdgcn_mfma_f32_16x16x32_bf16(
                        af, vf[nj], oacc[nj], 0, 0, 0);
                __builtin_amdgcn_s_setprio(0);
            }
            __syncthreads();
        }
#pragma unroll
        for (int nj = 0; nj < 4; nj++)
#pragma unroll
            for (int r = 0; r < 4; r++) {
                int row = q0 + w * 16 + lg * 4 + r;
                float v = oacc[nj][r] / lrun[r];
                outp[(size_t)(b * T_SEQ + row) * N_EMBD + h * HD + nj * 16 + lr] = f2bf(v);
            }
    }
}

extern "C" void kernel_launch(void* const* d_in, const int* in_sizes, int n_in,
                              void* d_out, int out_size, void* d_ws, size_t ws_size,
                              hipStream_t stream) {
    (void)in_sizes; (void)n_in; (void)out_size; (void)ws_size;
    const float* x      = (const float*)d_in[0];
    const float* ln1_g  = (const float*)d_in[1];
    const float* ln1_b  = (const float*)d_in[2];
    const float* w_attn = (const float*)d_in[3];
    const float* b_attn = (const float*)d_in[4];
    const float* w_proj = (const float*)d_in[5];
    const float* b_proj = (const float*)d_in[6];
    const float* ln2_g  = (const float*)d_in[7];
    const float* ln2_b  = (const float*)d_in[8];
    const float* w_fc   = (const float*)d_in[9];
    const float* b_fc   = (const float*)d_in[10];
    const float* w_fc2  = (const float*)d_in[11];
    const float* b_fc2  = (const float*)d_in[12];
    float* out = (float*)d_out;
    u16* ws = (u16*)d_ws;

    u16* wTa  = ws;                                      // [2304,768]
    u16* wTp  = wTa + (size_t)2304 * 768;                // [768,768]
    u16* wTf  = wTp + (size_t)768 * 768;                 // [3072,768]
    u16* wTf2 = wTf + (size_t)3072 * 768;                // [768,3072]
    u16* hbuf = wTf2 + (size_t)768 * 3072;               // [8192,768]
    u16* abuf = hbuf + (size_t)M_TOK * N_EMBD;           // [8192,768]
    u16* big  = abuf + (size_t)M_TOK * N_EMBD;           // [8192,2304] / [8192,3072]

    wconv<<<dim3(2304 / 64, 768 / 64), 256, 0, stream>>>(w_attn, wTa, 768, 2304);
    wconv<<<dim3(768 / 64, 768 / 64), 256, 0, stream>>>(w_proj, wTp, 768, 768);
    wconv<<<dim3(3072 / 64, 768 / 64), 256, 0, stream>>>(w_fc, wTf, 768, 3072);
    wconv<<<dim3(768 / 64, 3072 / 64), 256, 0, stream>>>(w_fc2, wTf2, 3072, 768);
    ln_bf16<<<M_TOK, 256, 0, stream>>>(x, ln1_g, ln1_b, hbuf);
    // qkv: [8192,2304] = hbuf @ wTa^T  (128x128 tile)
    gemm_bf16<0, 768, 128><<<dim3(18, 64), 256, 0, stream>>>(hbuf, wTa, b_attn, nullptr,
                                                             big, M_TOK, 3 * N_EMBD);
    attn_mfma<<<dim3(T_SEQ / QBLK / 2, NHEAD, BATCH), 256, 0, stream>>>(big, abuf);
    // proj: [8192,768] + residual -> fp32 (64x128 tile, 768 blocks = 3/CU)
    gemm_bf16<2, 768, 64><<<dim3(6, 128), 256, 0, stream>>>(abuf, wTp, b_proj, x,
                                                            out, M_TOK, N_EMBD);
    ln_bf16<<<M_TOK, 256, 0, stream>>>(out, ln2_g, ln2_b, hbuf);
    // fc: [8192,3072] gelu (128x128 tile)
    gemm_bf16<1, 768, 128><<<dim3(24, 64), 256, 0, stream>>>(hbuf, wTf, b_fc, nullptr,
                                                             big, M_TOK, 4 * N_EMBD);
    // fc2: [8192,768] + residual -> fp32 (64x128 tile, K=3072)
    gemm_bf16<2, 3072, 64><<<dim3(6, 128), 256, 0, stream>>>(big, wTf2, b_fc2, out,
                                                             out, M_TOK, N_EMBD);
}